// Round 12
// baseline (200.774 us; speedup 1.0000x reference)
//
#include <hip/hip_runtime.h>

// CIN (xDeepFM) fully-fused kernel for MI355X.
// B=4096, F=32, D=32; layer1: K1=1024 -> N=128; layer2: K2=4096 -> N=128.
// GEMM rows=(b,d); A generated in registers: A[(b,d)][h*M+m] = x0[b,h,d]*prev[b,m,d].
// mfma_f32_32x32x16_f16. Wave tile 4b x 64n (rt=4, ct=2), 2 waves/SIMD.
// R12 = R10 + address surgery: Wp padded 4 rows so the B-row sequence is
// linear (no wrap mask) -> single running per-lane pointer, all 8 B-loads
// per p-iter at immediate offsets {-4096,-3584,0,512}; x via running LDS
// pointer with p=7 peeled (mc-boundary reloads xqa/xqb). Theory: R10's
// VALUBusy=31% (3x static estimate) is compiler address materialization
// forced by the & wrap masks; MFMA+VALU share the issue path (67+31=98).

typedef _Float16 half_t;
typedef _Float16 half4v __attribute__((ext_vector_type(4)));
typedef _Float16 half8 __attribute__((ext_vector_type(8)));
typedef float f32x16 __attribute__((ext_vector_type(16)));

// ---- W pack (both filters, one launch): Wp[s][tg][n][8], k=h*M+mc*16+tg*8+j.
__global__ void prep_w_kernel(const float* __restrict__ W0,
                              const float* __restrict__ W1,
                              half_t* __restrict__ Wp0,
                              half_t* __restrict__ Wp1) {
  int gid = blockIdx.x * 256 + threadIdx.x;  // 320*256 threads
  int n = gid & 127;
  int tg = (gid >> 7) & 1;
  int s = gid >> 8;  // 0..319
  const float* W;
  half_t* Wp;
  int M, sl;
  if (s < 64) { W = W0; Wp = Wp0; M = 32; sl = s; }
  else        { W = W1; Wp = Wp1; M = 128; sl = s - 64; }
  int h = sl & 31, mc = sl >> 5;
  int kbase = h * M + mc * 16 + tg * 8;
  half8 v;
#pragma unroll
  for (int j = 0; j < 8; ++j) v[j] = (half_t)W[(size_t)(kbase + j) * 128 + n];
  *(half8*)(Wp + ((size_t)(sl * 2 + tg) * 128 + n) * 8) = v;
}

// swizzled prevT index: logical (row, m) -> halfs offset. 16B-chunk XOR spread.
__device__ __forceinline__ int pswz(int row, int m) {
  return row * 128 + (((m >> 3) ^ (row & 15)) << 3) + (m & 7);
}

__device__ __forceinline__ f32x16 mfma3216(half8 a, half8 b, f32x16 c) {
  return __builtin_amdgcn_mfma_f32_32x32x16_f16(a, b, c, 0, 0, 0);
}

template <bool L1>
__device__ __forceinline__ half8 p_read(const half_t* __restrict__ psrc,
                                        int row, int m) {
  return L1 ? *(const half8*)&psrc[row * 40 + m]
            : *(const half8*)&psrc[pswz(row, m)];
}

// One CIN layer: MC m-chunks x 32 h. B-rows linear across the layer (Wp has
// 4 pad rows at the end -> no wrap). Running pointers pw (B) / xp (x); p=7
// peeled (no x refill; mc boundary reloads xqa/xqb + P).
template <int MC, bool L1>
__device__ __forceinline__ void layer_loop(const half_t* __restrict__ Wp,
                                           const half_t* __restrict__ psrc,
                                           const half_t* __restrict__ xQw,
                                           int woff0, int rowb, int l31,
                                           int hi, f32x16 acc[4][2]) {
  const half_t* wpb = Wp + woff0;
  // preload rows 0..3 (ping = rows 0,1; pong = rows 2,3)
  half8 B0a0 = *(const half8*)(wpb);
  half8 B0a1 = *(const half8*)(wpb + 256);
  half8 B1a0 = *(const half8*)(wpb + 2048);
  half8 B1a1 = *(const half8*)(wpb + 2304);
  half8 B0b0 = *(const half8*)(wpb + 4096);
  half8 B0b1 = *(const half8*)(wpb + 4352);
  half8 B1b0 = *(const half8*)(wpb + 6144);
  half8 B1b1 = *(const half8*)(wpb + 6400);
  half8 xqa = *(const half8*)(xQw);        // hp 0 (h=0,1)
  half8 xqb = *(const half8*)(xQw + 512);  // hp 1 (h=2,3)
  half8 P[4];
#pragma unroll
  for (int rt = 0; rt < 4; ++rt)
    P[rt] = p_read<L1>(psrc, rowb + rt * 32 + l31, hi * 8);

  const half_t* pw = wpb + 5 * 2048;  // row 5 (ping refill = pw-2048/pw)

#pragma unroll 1
  for (int mc = 0; mc < MC; ++mc) {
    const half_t* xp = xQw + 1024;  // hp 2
#pragma unroll 1
    for (int p = 0; p < 7; ++p) {
      // ---- even gg: consume ping ----
#pragma unroll
      for (int rt = 0; rt < 4; ++rt) {
        half8 Af = P[rt] * xqa[rt * 2 + 0];
        acc[rt][0] = mfma3216(Af, B0a0, acc[rt][0]);
        acc[rt][1] = mfma3216(Af, B0a1, acc[rt][1]);
      }
#pragma unroll
      for (int rt = 0; rt < 4; ++rt) {
        half8 Af = P[rt] * xqa[rt * 2 + 1];
        acc[rt][0] = mfma3216(Af, B1a0, acc[rt][0]);
        acc[rt][1] = mfma3216(Af, B1a1, acc[rt][1]);
      }
      // refill ping (rows +4,+5)
      B0a0 = *(const half8*)(pw - 2048);
      B0a1 = *(const half8*)(pw - 1792);
      B1a0 = *(const half8*)(pw);
      B1a1 = *(const half8*)(pw + 256);
      xqa = *(const half8*)(xp);
      pw += 4096;
      // ---- odd gg: consume pong ----
#pragma unroll
      for (int rt = 0; rt < 4; ++rt) {
        half8 Af = P[rt] * xqb[rt * 2 + 0];
        acc[rt][0] = mfma3216(Af, B0b0, acc[rt][0]);
        acc[rt][1] = mfma3216(Af, B0b1, acc[rt][1]);
      }
#pragma unroll
      for (int rt = 0; rt < 4; ++rt) {
        half8 Af = P[rt] * xqb[rt * 2 + 1];
        acc[rt][0] = mfma3216(Af, B1b0, acc[rt][0]);
        acc[rt][1] = mfma3216(Af, B1b1, acc[rt][1]);
      }
      // refill pong (rows +6,+7)
      B0b0 = *(const half8*)(pw - 2048);
      B0b1 = *(const half8*)(pw - 1792);
      B1b0 = *(const half8*)(pw);
      B1b1 = *(const half8*)(pw + 256);
      xqb = *(const half8*)(xp + 512);
      pw += 4096;
      xp += 1024;
    }
    // ---- p = 7 (peeled: B refills only; x handled at mc boundary) ----
#pragma unroll
    for (int rt = 0; rt < 4; ++rt) {
      half8 Af = P[rt] * xqa[rt * 2 + 0];
      acc[rt][0] = mfma3216(Af, B0a0, acc[rt][0]);
      acc[rt][1] = mfma3216(Af, B0a1, acc[rt][1]);
    }
#pragma unroll
    for (int rt = 0; rt < 4; ++rt) {
      half8 Af = P[rt] * xqa[rt * 2 + 1];
      acc[rt][0] = mfma3216(Af, B1a0, acc[rt][0]);
      acc[rt][1] = mfma3216(Af, B1a1, acc[rt][1]);
    }
    B0a0 = *(const half8*)(pw - 2048);
    B0a1 = *(const half8*)(pw - 1792);
    B1a0 = *(const half8*)(pw);
    B1a1 = *(const half8*)(pw + 256);
    pw += 4096;
#pragma unroll
    for (int rt = 0; rt < 4; ++rt) {
      half8 Af = P[rt] * xqb[rt * 2 + 0];
      acc[rt][0] = mfma3216(Af, B0b0, acc[rt][0]);
      acc[rt][1] = mfma3216(Af, B0b1, acc[rt][1]);
    }
#pragma unroll
    for (int rt = 0; rt < 4; ++rt) {
      half8 Af = P[rt] * xqb[rt * 2 + 1];
      acc[rt][0] = mfma3216(Af, B1b0, acc[rt][0]);
      acc[rt][1] = mfma3216(Af, B1b1, acc[rt][1]);
    }
    B0b0 = *(const half8*)(pw - 2048);
    B0b1 = *(const half8*)(pw - 1792);
    B1b0 = *(const half8*)(pw);
    B1b1 = *(const half8*)(pw + 256);
    pw += 4096;
    if (mc + 1 < MC) {  // reload x (layer-periodic) and next-mc P
      xqa = *(const half8*)(xQw);
      xqb = *(const half8*)(xQw + 512);
      const int mn = (mc + 1) * 16 + hi * 8;
#pragma unroll
      for (int rt = 0; rt < 4; ++rt)
        P[rt] = p_read<L1>(psrc, rowb + rt * 32 + l31, mn);
    }
  }
}

__global__ __launch_bounds__(256, 2) void cin_fused_kernel(
    const float* __restrict__ x0,    // [4096][32][32] fp32
    const half_t* __restrict__ Wp0,  // 68*2048 halfs (4 pad rows)
    const half_t* __restrict__ Wp1,  // 260*2048 halfs (4 pad rows)
    float* __restrict__ out) {       // [4096][256]
  __shared__ half_t xQ[16 * 512];         // [hp][quad][d][rtl*2+(h&1)] (16 KB)
  __shared__ half_t prevT[8 * 32 * 128];  // swizzled [bi][d][m] (64 KB); alias xT
  half_t* xT = prevT;                     // [bi*32+d][h], stride 40 halfs

  const int tid = threadIdx.x;
  const int b0 = blockIdx.x * 8;

  // ---- stage x0 -> xQ and xT (8 b = 8192 floats = 2048 float4) ----
  const float4* x4 = (const float4*)(x0 + (size_t)b0 * 1024);
#pragma unroll
  for (int r = 0; r < 8; ++r) {
    int q = r * 256 + tid;
    float4 v = x4[q];
    int e4 = q * 4;
    int bi = e4 >> 10, h = (e4 >> 5) & 31, d0 = e4 & 31;
    half4v hv = {(half_t)v.x, (half_t)v.y, (half_t)v.z, (half_t)v.w};
    const int quad = bi >> 2, rtl = bi & 3;
#pragma unroll
    for (int j = 0; j < 4; ++j) {
      xQ[(h >> 1) * 512 + quad * 256 + (d0 + j) * 8 + rtl * 2 + (h & 1)] =
          hv[j];
      xT[(bi * 32 + d0 + j) * 40 + h] = hv[j];
    }
  }
  __syncthreads();

  const int lane = tid & 63;
  const int l31 = lane & 31;
  const int hi = lane >> 5;
  const int wave = tid >> 6;
  const int wr = wave >> 1;  // b-quad: b's wr*4 .. wr*4+3
  const int wc = wave & 1;   // col half: n in [wc*64, wc*64+64)

  const int woff0 = hi * 1024 + (wc * 64 + l31) * 8;  // ct=0 B offset (halfs)
  const int rowb = wr * 128;                          // P row base
  const half_t* xQw = xQ + wr * 256 + l31 * 8;

  f32x16 acc[4][2];
#pragma unroll
  for (int rt = 0; rt < 4; ++rt)
#pragma unroll
    for (int ct = 0; ct < 2; ++ct)
#pragma unroll
      for (int r = 0; r < 16; ++r) acc[rt][ct][r] = 0.f;

  // ================= layer 1 =================
  layer_loop<2, true>(Wp0, xT, xQw, woff0, rowb, l31, hi, acc);

  __syncthreads();  // all waves done reading xT before prevT overwrite

  // ---- epilogue 1: relu, cur1 -> prevT (swizzled), d-sum -> out[:, 0:128] --
#pragma unroll
  for (int rt = 0; rt < 4; ++rt) {
#pragma unroll
    for (int ct = 0; ct < 2; ++ct) {
      float s = 0.f;
#pragma unroll
      for (int r = 0; r < 16; ++r) {
        float v = acc[rt][ct][r];
        v = v > 0.f ? v : 0.f;
        s += v;
        int d = (r & 3) + ((r >> 2) << 3) + hi * 4;  // C/D row map (32x32)
        prevT[pswz(rowb + rt * 32 + d, wc * 64 + ct * 32 + l31)] = (half_t)v;
        acc[rt][ct][r] = 0.f;
      }
      s += __shfl_down(s, 32);
      if (lane < 32)
        out[(size_t)(b0 + wr * 4 + rt) * 256 + wc * 64 + ct * 32 + lane] = s;
    }
  }
  __syncthreads();

  // ================= layer 2 =================
  layer_loop<8, false>(Wp1, prevT, xQw, woff0, rowb, l31, hi, acc);

  // ---- epilogue 2: relu, d-sum -> out[:, 128:256] ----
#pragma unroll
  for (int rt = 0; rt < 4; ++rt) {
#pragma unroll
    for (int ct = 0; ct < 2; ++ct) {
      float s = 0.f;
#pragma unroll
      for (int r = 0; r < 16; ++r) {
        float v = acc[rt][ct][r];
        s += v > 0.f ? v : 0.f;
      }
      s += __shfl_down(s, 32);
      if (lane < 32)
        out[(size_t)(b0 + wr * 4 + rt) * 256 + 128 + wc * 64 + ct * 32 +
            lane] = s;
    }
  }
}

extern "C" void kernel_launch(void* const* d_in, const int* in_sizes, int n_in,
                              void* d_out, int out_size, void* d_ws,
                              size_t ws_size, hipStream_t stream) {
  const float* x0 = (const float*)d_in[0];  // [4096,32,32]
  const float* w0 = (const float*)d_in[1];  // [1,1024,128]
  const float* w1 = (const float*)d_in[2];  // [1,4096,128]
  float* out = (float*)d_out;               // [4096,256]
  char* ws = (char*)d_ws;

  half_t* Wp0 = (half_t*)(ws);                  // 68*2048 f16 (64 + 4 pad)
  half_t* Wp1 = (half_t*)(ws + 68 * 2048 * 2);  // 260*2048 f16 (256 + 4 pad)

  hipLaunchKernelGGL(prep_w_kernel, dim3(320), dim3(256), 0, stream, w0, w1,
                     Wp0, Wp1);
  hipLaunchKernelGGL(cin_fused_kernel, dim3(512), dim3(256), 0, stream, x0,
                     Wp0, Wp1, out);
}